// Round 4
// baseline (724.133 us; speedup 1.0000x reference)
//
#include <hip/hip_runtime.h>
#include <hip/hip_bf16.h>
#include <stdint.h>

#define H       256
#define INDIM   64
#define TSTEPS  128
#define BATCH   2048
#define MROWS   8
#define OUTD    4

typedef __attribute__((ext_vector_type(8))) short bf16x8;
typedef __attribute__((ext_vector_type(4))) float f32x4;

__device__ __forceinline__ short b2s(float x) {
  __hip_bfloat16 h = __float2bfloat16(x);
  return __builtin_bit_cast(short, h);
}

// ---- bank-conflict-free swizzle for the [8][256] bf16 tiles ----
// 16B fragment (row, kt, g) -> bank-group grp (byte bits 6:4). HW serves
// ds_read_b128 in chunks {4n+i + 16j}; within a chunk (row>>2, kt fixed;
// i=row&3, j=g vary) grp hits each of 8 groups exactly 2x -> free (m136).
// Writes: row>>2 and g>>1 both enter the bank bits -> 2-way max (same-dword).
__device__ __forceinline__ int grp(int row, int kt, int g) {
  return (((row ^ g) & 3) << 1) | (((g >> 1) ^ kt ^ (row >> 2)) & 1);
}
// short index of element (row, col) in the swizzled [8][256] tile
__device__ __forceinline__ int sidx(int row, int col) {
  const int kt = col >> 5, g = (col >> 3) & 3, u = col & 7;
  return row * 256 + ((kt >> 1) << 6) + grp(row, kt, g) * 8 + u;
}
// conflict-free slot permutation for wpk_lds (64 slots of 8 shorts)
__device__ __forceinline__ int wpk_slot(int lane) {
  return (((lane & 3) << 1) | ((lane >> 4) & 1)) |
         (((lane >> 2) & 3) << 3) | (((lane >> 5) & 1) << 5);
}

// lanes 0-31 keep a; lanes 32-63 receive b from (lane-32).
__device__ __forceinline__ float swap_hilo(float a, float b) {
#if __has_builtin(__builtin_amdgcn_permlane32_swap)
  typedef unsigned int u32x2 __attribute__((ext_vector_type(2)));
  u32x2 r = __builtin_amdgcn_permlane32_swap(
      __builtin_bit_cast(unsigned int, a),
      __builtin_bit_cast(unsigned int, b), false, false);
  return __builtin_bit_cast(float, r[0]);
#else
  float t = __shfl_xor(b, 32);
  return (threadIdx.x & 32) ? t : a;
#endif
}

#define MFMA(a, b, c) __builtin_amdgcn_mfma_f32_16x16x32_bf16((a), (b), (c), 0, 0, 0)

__global__ __launch_bounds__(512, 1) void node_kernel(
    const float* __restrict__ g_static, const float* __restrict__ g_times,
    const float* __restrict__ g_Win, const float* __restrict__ g_bin,
    const float* __restrict__ g_W1, const float* __restrict__ g_b1,
    const float* __restrict__ g_W2, const float* __restrict__ g_b2,
    const float* __restrict__ g_Wpk, const float* __restrict__ g_bpk,
    const float* __restrict__ g_Wpd, const float* __restrict__ g_bpd,
    float* __restrict__ g_out)
{
  __shared__ __align__(16) short arg_lds[MROWS * H];
  __shared__ __align__(16) short h1_lds[MROWS * H];
  __shared__ __align__(16) short wpk_lds[8 * 64 * 8];
  __shared__ float h_lds[MROWS * H];
  __shared__ float s_lds[MROWS * INDIM];
  __shared__ float t_lds[TSTEPS];

  const int tid   = threadIdx.x;
  const int lane  = tid & 63;
  const int wid   = tid >> 6;
  const int g     = lane >> 4;       // 0..3
  const int c     = lane & 15;
  const int b0    = blockIdx.x * MROWS;
  const int ncol0 = wid * 32;
  const int am    = lane & 7;        // A-frag row (rows 8..15 broadcast-duplicate 0..7)
  const int gg    = (lane >> 4) & 1;
  const int hh    = lane >> 5;
  const int colu  = ncol0 + 16 * hh + c;
  const int dm    = 4 * g;

  if (tid < TSTEPS) t_lds[tid] = g_times[tid];

  const float b1u2 = 2.0f * g_b1[colu];
  const float b2u  = g_b2[colu];
  const float bpkc = g_bpk[c & 3];
  const float bpdv = g_bpd[0];
  float wpd[4];
#pragma unroll
  for (int j = 0; j < 4; ++j) wpd[j] = g_Wpd[lane + 64 * j];

  // ---- loop-invariant swizzled LDS element indices ----
  int ra[8], wa[4], ha[4];
#pragma unroll
  for (int kt = 0; kt < 8; ++kt) ra[kt] = sidx(am, kt * 32 + g * 8);
#pragma unroll
  for (int r = 0; r < 4; ++r) {
    wa[r] = sidx(4 * gg + r, colu);
    ha[r] = (4 * gg + r) * H + colu;
  }

  // ---- W1,W2 -> bf16 B-fragments in registers ----
  bf16x8 w1f[8][2], w2f[8][2];
#pragma unroll
  for (int kt = 0; kt < 8; ++kt) {
#pragma unroll
    for (int nt = 0; nt < 2; ++nt) {
      const int n  = ncol0 + nt * 16 + c;
      const int kb = kt * 32 + g * 8;
      bf16x8 f1, f2;
#pragma unroll
      for (int u = 0; u < 8; ++u) {
        f1[u] = b2s(g_W1[(kb + u) * H + n]);
        f2[u] = b2s(g_W2[(kb + u) * H + n]);
      }
      w1f[kt][nt] = f1;
      w2f[kt][nt] = f2;
    }
  }

  // ---- Wpk B-fragments -> LDS (wave 0), conflict-free slot layout ----
  if (wid == 0) {
    const int slot = wpk_slot(lane);
#pragma unroll
    for (int kt = 0; kt < 8; ++kt) {
      bf16x8 f;
#pragma unroll
      for (int u = 0; u < 8; ++u) {
        const int k = kt * 32 + g * 8 + u;
        f[u] = (c < OUTD) ? b2s(g_Wpk[k * OUTD + c]) : (short)0;
      }
      *(bf16x8*)(wpk_lds + kt * 512 + slot * 8) = f;
    }
  }

  // ---- h0 = static @ W_in + b_in ----
  s_lds[tid] = g_static[(b0 + (tid >> 6)) * INDIM + (tid & 63)];
  __syncthreads();
  {
    const int m  = tid >> 6;
    const int n0 = (tid & 63) * 4;
    float a0 = g_bin[n0], a1 = g_bin[n0 + 1], a2 = g_bin[n0 + 2], a3 = g_bin[n0 + 3];
#pragma unroll 8
    for (int k = 0; k < INDIM; ++k) {
      const float sv = s_lds[m * INDIM + k];
      const f32x4 w = *(const f32x4*)(g_Win + k * H + n0);
      a0 += sv * w[0]; a1 += sv * w[1]; a2 += sv * w[2]; a3 += sv * w[3];
    }
    h_lds[m * H + n0] = a0;     h_lds[m * H + n0 + 1] = a1;
    h_lds[m * H + n0 + 2] = a2; h_lds[m * H + n0 + 3] = a3;
    arg_lds[sidx(m, n0)]     = b2s(a0);
    arg_lds[sidx(m, n0 + 1)] = b2s(a1);
    arg_lds[sidx(m, n0 + 2)] = b2s(a2);
    arg_lds[sidx(m, n0 + 3)] = b2s(a3);
  }
  __syncthreads();

  float hb[4];
#pragma unroll
  for (int r = 0; r < 4; ++r) hb[r] = h_lds[ha[r]];

  const int wslot = wpk_slot(lane);
  auto emit_pk = [&](int t) {
    if (wid == 0) {
      f32x4 acc = {0.f, 0.f, 0.f, 0.f};
#pragma unroll
      for (int kt = 0; kt < 8; ++kt) {
        const bf16x8 aA = *(const bf16x8*)(arg_lds + ra[kt]);
        const bf16x8 bW = *(const bf16x8*)(wpk_lds + kt * 512 + wslot * 8);
        acc = MFMA(aA, bW, acc);
      }
      if (g < 2 && c < OUTD) {
#pragma unroll
        for (int r = 0; r < 4; ++r)
          g_out[((size_t)(b0 + dm + r) * TSTEPS + t) * OUTD + c] = acc[r] + bpkc;
      }
    }
  };

  emit_pk(0);

  const f32x4 vz = {0.f, 0.f, 0.f, 0.f};
  for (int t = 1; t < TSTEPS; ++t) {
    const float dt = t_lds[t] - t_lds[t - 1];
    const float s6 = dt * (1.0f / 6.0f);
    float ks[4];

#pragma unroll
    for (int ev = 0; ev < 4; ++ev) {
      // ---- phase 1: h1 = tanh(arg @ W1 + b1) ----
      // 8 independent depth-2 MFMA chains (latency tail halved vs depth-4).
      {
        const bf16x8 f0 = *(const bf16x8*)(arg_lds + ra[0]);
        const bf16x8 f1 = *(const bf16x8*)(arg_lds + ra[1]);
        const bf16x8 f2 = *(const bf16x8*)(arg_lds + ra[2]);
        const bf16x8 f3 = *(const bf16x8*)(arg_lds + ra[3]);
        const bf16x8 f4 = *(const bf16x8*)(arg_lds + ra[4]);
        const bf16x8 f5 = *(const bf16x8*)(arg_lds + ra[5]);
        const bf16x8 f6 = *(const bf16x8*)(arg_lds + ra[6]);
        const bf16x8 f7 = *(const bf16x8*)(arg_lds + ra[7]);
        f32x4 c00 = vz, c01 = vz, c02 = vz, c03 = vz;
        f32x4 c10 = vz, c11 = vz, c12 = vz, c13 = vz;
        c00 = MFMA(f0, w1f[0][0], c00); c10 = MFMA(f0, w1f[0][1], c10);
        c01 = MFMA(f2, w1f[2][0], c01); c11 = MFMA(f2, w1f[2][1], c11);
        c02 = MFMA(f4, w1f[4][0], c02); c12 = MFMA(f4, w1f[4][1], c12);
        c03 = MFMA(f6, w1f[6][0], c03); c13 = MFMA(f6, w1f[6][1], c13);
        c00 = MFMA(f1, w1f[1][0], c00); c10 = MFMA(f1, w1f[1][1], c10);
        c01 = MFMA(f3, w1f[3][0], c01); c11 = MFMA(f3, w1f[3][1], c11);
        c02 = MFMA(f5, w1f[5][0], c02); c12 = MFMA(f5, w1f[5][1], c12);
        c03 = MFMA(f7, w1f[7][0], c03); c13 = MFMA(f7, w1f[7][1], c13);
        const f32x4 S0 = (c00 + c01) + (c02 + c03);
        const f32x4 S1 = (c10 + c11) + (c12 + c13);
#pragma unroll
        for (int r = 0; r < 4; ++r) {
          const float v = swap_hilo(S0[r], S1[r]);
          const float e = __expf(__builtin_fmaf(2.0f, v, b1u2));
          const float th = 1.0f - __fdividef(2.0f, e + 1.0f);
          h1_lds[wa[r]] = b2s(th);
        }
      }
      __syncthreads();

      // ---- phase 2: k = h1 @ W2 + b2, RK4 update ----
      {
        const bf16x8 f0 = *(const bf16x8*)(h1_lds + ra[0]);
        const bf16x8 f1 = *(const bf16x8*)(h1_lds + ra[1]);
        const bf16x8 f2 = *(const bf16x8*)(h1_lds + ra[2]);
        const bf16x8 f3 = *(const bf16x8*)(h1_lds + ra[3]);
        const bf16x8 f4 = *(const bf16x8*)(h1_lds + ra[4]);
        const bf16x8 f5 = *(const bf16x8*)(h1_lds + ra[5]);
        const bf16x8 f6 = *(const bf16x8*)(h1_lds + ra[6]);
        const bf16x8 f7 = *(const bf16x8*)(h1_lds + ra[7]);
        f32x4 c00 = vz, c01 = vz, c02 = vz, c03 = vz;
        f32x4 c10 = vz, c11 = vz, c12 = vz, c13 = vz;
        c00 = MFMA(f0, w2f[0][0], c00); c10 = MFMA(f0, w2f[0][1], c10);
        c01 = MFMA(f2, w2f[2][0], c01); c11 = MFMA(f2, w2f[2][1], c11);
        c02 = MFMA(f4, w2f[4][0], c02); c12 = MFMA(f4, w2f[4][1], c12);
        c03 = MFMA(f6, w2f[6][0], c03); c13 = MFMA(f6, w2f[6][1], c13);
        c00 = MFMA(f1, w2f[1][0], c00); c10 = MFMA(f1, w2f[1][1], c10);
        c01 = MFMA(f3, w2f[3][0], c01); c11 = MFMA(f3, w2f[3][1], c11);
        c02 = MFMA(f5, w2f[5][0], c02); c12 = MFMA(f5, w2f[5][1], c12);
        c03 = MFMA(f7, w2f[7][0], c03); c13 = MFMA(f7, w2f[7][1], c13);
        const f32x4 S0 = (c00 + c01) + (c02 + c03);
        const f32x4 S1 = (c10 + c11) + (c12 + c13);
#pragma unroll
        for (int r = 0; r < 4; ++r) {
          const float kv = swap_hilo(S0[r], S1[r]) + b2u;
          if (ev == 0)      ks[r] = kv;
          else if (ev == 3) ks[r] += kv;
          else              ks[r] += 2.0f * kv;
          if (ev < 3) {
            const float cc = (ev == 2) ? dt : 0.5f * dt;
            arg_lds[wa[r]] = b2s(__builtin_fmaf(cc, kv, hb[r]));
          } else {
            hb[r] = __builtin_fmaf(s6, ks[r], hb[r]);
            arg_lds[wa[r]] = b2s(hb[r]);
          }
        }
      }
      __syncthreads();
    }
    emit_pk(t);
  }

  // ---- pd = h_T @ W_pd + b_pd ----
#pragma unroll
  for (int r = 0; r < 4; ++r) h_lds[ha[r]] = hb[r];
  __syncthreads();
  {
    float p = 0.0f;
#pragma unroll
    for (int j = 0; j < 4; ++j) p += h_lds[wid * H + lane + 64 * j] * wpd[j];
#pragma unroll
    for (int m = 1; m < 64; m <<= 1) p += __shfl_xor(p, m);
    if (lane == 0) g_out[(size_t)BATCH * TSTEPS * OUTD + b0 + wid] = p + bpdv;
  }
}

extern "C" void kernel_launch(void* const* d_in, const int* in_sizes, int n_in,
                              void* d_out, int out_size, void* d_ws, size_t ws_size,
                              hipStream_t stream) {
  const float* g_static = (const float*)d_in[0];
  const float* g_times  = (const float*)d_in[1];
  const float* g_Win    = (const float*)d_in[2];
  const float* g_bin    = (const float*)d_in[3];
  const float* g_W1     = (const float*)d_in[4];
  const float* g_b1     = (const float*)d_in[5];
  const float* g_W2     = (const float*)d_in[6];
  const float* g_b2     = (const float*)d_in[7];
  const float* g_Wpk    = (const float*)d_in[8];
  const float* g_bpk    = (const float*)d_in[9];
  const float* g_Wpd    = (const float*)d_in[10];
  const float* g_bpd    = (const float*)d_in[11];

  node_kernel<<<dim3(BATCH / MROWS), dim3(512), 0, stream>>>(
      g_static, g_times, g_Win, g_bin, g_W1, g_b1, g_W2, g_b2,
      g_Wpk, g_bpk, g_Wpd, g_bpd, (float*)d_out);
}